// Round 1
// 1896.755 us; speedup vs baseline: 1.5799x; 1.5799x over previous
//
#include <hip/hip_runtime.h>
#include <math.h>

#define NB 256    // batch
#define NH 256    // hidden
#define NE 128    // embed
#define NV 32000  // vocab
#define TT 16     // timesteps
#define NZ 64     // noise dim

#define MAXC 192        // candidate slots per (t,b) row
#define UTHR 0.9979f    // u > UTHR  <=>  gumbel(u) > ~6.1647 ; E[count] ~ 67
#define GNC  6.17f      // conservative upper bound on gumbel of any non-candidate

// ---------- helpers ----------
__device__ __forceinline__ unsigned fkey(float f) {
    unsigned u = __float_as_uint(f);
    return (u & 0x80000000u) ? ~u : (u | 0x80000000u);
}
__device__ __forceinline__ float unfkey(unsigned k) {
    return __uint_as_float((k & 0x80000000u) ? (k & 0x7fffffffu) : ~k);
}
__device__ __forceinline__ unsigned long long sx64(unsigned long long v, int m) {
    unsigned lo = (unsigned)__shfl_xor((int)(unsigned)(v & 0xffffffffull), m, 64);
    unsigned hi = (unsigned)__shfl_xor((int)(unsigned)(v >> 32), m, 64);
    return ((unsigned long long)hi << 32) | (unsigned long long)lo;
}

// ---------- h0 = tanh(noise @ fcW^T + fcb); c0 = 0; init maxWn ----------
__global__ void k_init(const float* __restrict__ noise, const float* __restrict__ fcW,
                       const float* __restrict__ fcb, float* __restrict__ h,
                       float* __restrict__ c, unsigned* __restrict__ maxWnU) {
    __shared__ float ns[NZ];
    int b = blockIdx.x, tid = threadIdx.x;
    if (tid < NZ) ns[tid] = noise[b * NZ + tid];
    __syncthreads();
    float acc = fcb[tid];
    const float* w = &fcW[(size_t)tid * NZ];
#pragma unroll
    for (int k = 0; k < NZ; k++) acc += ns[k] * w[k];
    h[b * NH + tid] = tanhf(acc);
    c[b * NH + tid] = 0.f;
    if (b == 0 && tid == 0) *maxWnU = 0u;
}

// ---------- maxWn = max_v ||out_W[v]||_2 (once; also warms W into L2/L3) ----------
__global__ __launch_bounds__(256) void k_wnorm(const float* __restrict__ W,
                                               unsigned* __restrict__ maxWnU) {
    int lane = threadIdx.x & 63;
    int wv = blockIdx.x * 4 + (threadIdx.x >> 6);  // 125 blocks * 4 waves = 500 waves
    float best = 0.f;
    for (int r = wv * 64; r < wv * 64 + 64; r++) {
        const float* row = &W[(size_t)r * NH];
        float p = 0.f;
#pragma unroll
        for (int q = 0; q < 4; q++) {
            float x = row[lane + 64 * q];
            p += x * x;
        }
#pragma unroll
        for (int m = 1; m <= 32; m <<= 1) p += __shfl_xor(p, m, 64);
        best = fmaxf(best, p);
    }
    // positive floats: uint bit order == float order
    if (lane == 0) atomicMax(maxWnU, __float_as_uint(sqrtf(best) * 1.0001f + 1e-6f));
}

// ---------- fused: zero output + extract gumbel candidates per (t,b) row ----------
// One block per row r = t*NB + b. Candidates are u > UTHR (monotone in u, no logs
// needed for rejects). LDS-local list, no global atomics.
__global__ __launch_bounds__(256) void k_prep(const float* __restrict__ gu,
                                              float* __restrict__ out,
                                              int* __restrict__ counts,
                                              float2* __restrict__ cands) {
    __shared__ int cnt;
    __shared__ float2 lc[MAXC];
    int r = blockIdx.x;  // t*NB + b
    int t = r >> 8, b = r & 255;
    int tid = threadIdx.x;
    if (tid == 0) cnt = 0;
    __syncthreads();
    const float4* g4 = (const float4*)gu + (size_t)r * (NV / 4);
    float4* o4 = (float4*)out + ((size_t)b * TT + t) * (NV / 4);
    float4 z = make_float4(0.f, 0.f, 0.f, 0.f);
    for (int i = tid; i < NV / 4; i += 256) {
        float4 u = g4[i];
        o4[i] = z;
        float uv[4] = {u.x, u.y, u.z, u.w};
#pragma unroll
        for (int comp = 0; comp < 4; comp++) {
            if (uv[comp] > UTHR) {
                int k = atomicAdd(&cnt, 1);  // LDS atomic
                if (k < MAXC) {
                    float gm = -logf(-logf(uv[comp] + 1e-10f) + 1e-10f);
                    lc[k] = make_float2(gm, __int_as_float(i * 4 + comp));
                }
            }
        }
    }
    __syncthreads();
    int n = cnt > MAXC ? MAXC : cnt;
    if (tid == 0) counts[r] = cnt;  // cnt > MAXC signals fallback
    if (tid < n) cands[(size_t)r * MAXC + tid] = lc[tid];
}

// ---------- gates = [x | h] @ [Wih | Whh]^T + bih + bhh (fp32) ----------
__global__ __launch_bounds__(256) void k_gates(
    const float* __restrict__ h, const float* __restrict__ embW,
    const float* __restrict__ Wih, const float* __restrict__ Whh,
    const float* __restrict__ bih, const float* __restrict__ bhh,
    float* __restrict__ gates, const int* __restrict__ idxPrev, int t) {
    __shared__ float As[16][68];
    __shared__ float Ws[16][68];
    __shared__ int idxs[64];
    int tid = threadIdx.x;
    int n0 = blockIdx.x * 64, m0 = blockIdx.y * 64;
    if (tid < 64) {
        idxs[tid] = (t == 0) ? 0 : idxPrev[m0 + tid];
    }
    float acc[4][4] = {};
    int row = tid >> 2, kq = tid & 3;
    int ty = tid >> 4, tx = tid & 15;
    for (int kc = 0; kc < 24; kc++) {
        __syncthreads();
        int kg = kc * 16 + kq * 4;
        float4 a4, w4;
        if (kg < NE) {
            a4 = *(const float4*)&embW[(size_t)idxs[row] * NE + kg];
            w4 = *(const float4*)&Wih[(size_t)(n0 + row) * NE + kg];
        } else {
            a4 = *(const float4*)&h[(size_t)(m0 + row) * NH + kg - NE];
            w4 = *(const float4*)&Whh[(size_t)(n0 + row) * NH + kg - NE];
        }
        As[kq * 4 + 0][row] = a4.x; As[kq * 4 + 1][row] = a4.y;
        As[kq * 4 + 2][row] = a4.z; As[kq * 4 + 3][row] = a4.w;
        Ws[kq * 4 + 0][row] = w4.x; Ws[kq * 4 + 1][row] = w4.y;
        Ws[kq * 4 + 2][row] = w4.z; Ws[kq * 4 + 3][row] = w4.w;
        __syncthreads();
#pragma unroll
        for (int kk = 0; kk < 16; kk++) {
            float a[4], w[4];
            *(float4*)&a[0] = *(const float4*)&As[kk][ty * 4];
            *(float4*)&w[0] = *(const float4*)&Ws[kk][tx * 4];
#pragma unroll
            for (int i = 0; i < 4; i++)
#pragma unroll
                for (int j = 0; j < 4; j++) acc[i][j] += a[i] * w[j];
        }
    }
#pragma unroll
    for (int i = 0; i < 4; i++) {
        int b = m0 + ty * 4 + i;
#pragma unroll
        for (int j = 0; j < 4; j++) {
            int n = n0 + tx * 4 + j;
            gates[(size_t)b * (4 * NH) + n] = acc[i][j] + bih[n] + bhh[n];
        }
    }
}

// ---------- fused LSTM pointwise + certified candidate argmax + one-hot ----------
// One block per batch row. Candidate logits are exact fp32 dots. Certificate:
// best_s >= GNC + ||h||2 * maxWn + margin  =>  no non-candidate can win.
// Otherwise: exact block-local full scan of all 32000 (correctness escape hatch).
__global__ __launch_bounds__(256) void k_cellcand(
    const float* __restrict__ gates, float* __restrict__ c, float* __restrict__ h,
    const int* __restrict__ counts, const float2* __restrict__ cands,
    const float* __restrict__ W, const float* __restrict__ outb,
    const float* __restrict__ gu, const unsigned* __restrict__ maxWnU,
    int* __restrict__ idxs, float* __restrict__ out, int t) {
    __shared__ float hsh[NH];
    __shared__ float hred[4];
    __shared__ unsigned long long bks[4];
    __shared__ int fbflag;
    int b = blockIdx.x, tid = threadIdx.x;
    int lane = tid & 63, w = tid >> 6;

    // LSTM cell pointwise
    const float* g = &gates[(size_t)b * (4 * NH)];
    float ig = g[tid], fg = g[NH + tid], gg = g[2 * NH + tid], og = g[3 * NH + tid];
    float is = 1.f / (1.f + expf(-ig));
    float fs = 1.f / (1.f + expf(-fg));
    float gt = tanhf(gg);
    float os = 1.f / (1.f + expf(-og));
    float cn = fs * c[b * NH + tid] + is * gt;
    c[b * NH + tid] = cn;
    float hv = os * tanhf(cn);
    h[b * NH + tid] = hv;
    hsh[tid] = hv;
    float p = hv * hv;
#pragma unroll
    for (int m = 1; m <= 32; m <<= 1) p += __shfl_xor(p, m, 64);
    if (lane == 0) hred[w] = p;
    __syncthreads();

    // candidate evaluation: one wave per candidate (coalesced W row, conflict-free LDS)
    int r = t * NB + b;
    int nc = counts[r];
    unsigned long long bk = 0;
    if (nc >= 1 && nc <= MAXC) {
        const float2* cr = &cands[(size_t)r * MAXC];
        for (int ci = w; ci < nc; ci += 4) {
            float2 cd = cr[ci];
            int v = __float_as_int(cd.y);
            const float* Wr = &W[(size_t)v * NH];
            float d = 0.f;
#pragma unroll
            for (int q = 0; q < 4; q++) d += hsh[lane + 64 * q] * Wr[lane + 64 * q];
#pragma unroll
            for (int m = 1; m <= 32; m <<= 1) d += __shfl_xor(d, m, 64);
            float s = d + outb[v] + cd.x;
            unsigned long long key =
                ((unsigned long long)fkey(s) << 32) | (unsigned)(NV - 1 - v);
            if (key > bk) bk = key;  // tie -> smaller idx
        }
    }
    if (lane == 0) bks[w] = bk;
    __syncthreads();
    if (tid == 0) {
        unsigned long long k = bks[0];
        for (int q = 1; q < 4; q++)
            if (bks[q] > k) k = bks[q];
        bks[0] = k;
        float hh2 = hred[0] + hred[1] + hred[2] + hred[3];
        float D = sqrtf(hh2) * 1.0001f * __uint_as_float(*maxWnU) + 0.01f;
        float bs = unfkey((unsigned)(k >> 32));
        fbflag = (nc < 1 || nc > MAXC || !(bs >= GNC + D)) ? 1 : 0;
    }
    __syncthreads();
    if (fbflag) {  // block-uniform; ~never taken
        const float* gur = &gu[((size_t)t * NB + b) * NV];
        unsigned long long fk = 0;
        for (int v = tid; v < NV; v += 256) {
            float uv = gur[v];
            float gm = -logf(-logf(uv + 1e-10f) + 1e-10f);
            const float* Wr = &W[(size_t)v * NH];
            float d = 0.f;
            for (int k2 = 0; k2 < NH; k2++) d += hsh[k2] * Wr[k2];
            float s = d + outb[v] + gm;
            unsigned long long key =
                ((unsigned long long)fkey(s) << 32) | (unsigned)(NV - 1 - v);
            if (key > fk) fk = key;
        }
#pragma unroll
        for (int m = 1; m <= 32; m <<= 1) {
            unsigned long long o = sx64(fk, m);
            if (o > fk) fk = o;
        }
        if (lane == 0) bks[w] = fk;
        __syncthreads();
        if (tid == 0) {
            unsigned long long k = bks[0];
            for (int q = 1; q < 4; q++)
                if (bks[q] > k) k = bks[q];
            bks[0] = k;
        }
        __syncthreads();
    }
    if (tid == 0) {
        unsigned long long k = bks[0];
        int v = NV - 1 - (int)(unsigned)(k & 0xffffffffu);
        idxs[t * NB + b] = v;
        out[((size_t)b * TT + t) * NV + v] = 1.0f;
    }
}

extern "C" void kernel_launch(void* const* d_in, const int* in_sizes, int n_in,
                              void* d_out, int out_size, void* d_ws, size_t ws_size,
                              hipStream_t stream) {
    const float* noise = (const float*)d_in[0];
    const float* gu    = (const float*)d_in[1];
    const float* fcW   = (const float*)d_in[2];
    const float* fcb   = (const float*)d_in[3];
    const float* embW  = (const float*)d_in[4];
    const float* Wih   = (const float*)d_in[5];
    const float* Whh   = (const float*)d_in[6];
    const float* bih   = (const float*)d_in[7];
    const float* bhh   = (const float*)d_in[8];
    const float* outW  = (const float*)d_in[9];
    const float* outb  = (const float*)d_in[10];
    float* out = (float*)d_out;

    float* ws = (float*)d_ws;
    float* h      = ws;                               // 65536 f
    float* c      = ws + 65536;                       // 65536 f
    float* gates  = ws + 131072;                      // 262144 f
    int* idxs     = (int*)(ws + 393216);              // 4096 i32
    int* counts   = (int*)(ws + 397312);              // 4096 i32
    unsigned* maxWnU = (unsigned*)(ws + 401408);      // 1 u32
    float2* cands = (float2*)(ws + 401416);           // 4096*192 float2 (6 MB), 8B-aligned

    k_init<<<NB, NH, 0, stream>>>(noise, fcW, fcb, h, c, maxWnU);
    k_wnorm<<<125, 256, 0, stream>>>(outW, maxWnU);
    k_prep<<<TT * NB, 256, 0, stream>>>(gu, out, counts, cands);

    for (int t = 0; t < TT; t++) {
        const int* idxPrev = idxs + (t > 0 ? (t - 1) * NB : 0);
        k_gates<<<dim3(16, 4), 256, 0, stream>>>(h, embW, Wih, Whh, bih, bhh, gates,
                                                 idxPrev, t);
        k_cellcand<<<NB, 256, 0, stream>>>(gates, c, h, counts, cands, outW, outb, gu,
                                           maxWnU, idxs, out, t);
    }
}

// Round 2
// 1797.003 us; speedup vs baseline: 1.6676x; 1.0555x over previous
//
#include <hip/hip_runtime.h>
#include <math.h>

#define NB 256    // batch
#define NH 256    // hidden
#define NE 128    // embed
#define NV 32000  // vocab
#define TT 16     // timesteps
#define NZ 64     // noise dim

#define MAXC 192        // candidate slots per (t,b) row
#define UTHR 0.9979f    // u > UTHR  <=>  gumbel(u) > ~6.1647 ; E[count] ~ 67
#define GNC  6.17f      // conservative upper bound on gumbel of any non-candidate

typedef __attribute__((ext_vector_type(4))) float f32x4;

// ---------- helpers ----------
__device__ __forceinline__ unsigned fkey(float f) {
    unsigned u = __float_as_uint(f);
    return (u & 0x80000000u) ? ~u : (u | 0x80000000u);
}
__device__ __forceinline__ float unfkey(unsigned k) {
    return __uint_as_float((k & 0x80000000u) ? (k & 0x7fffffffu) : ~k);
}
__device__ __forceinline__ unsigned long long sx64(unsigned long long v, int m) {
    unsigned lo = (unsigned)__shfl_xor((int)(unsigned)(v & 0xffffffffull), m, 64);
    unsigned hi = (unsigned)__shfl_xor((int)(unsigned)(v >> 32), m, 64);
    return ((unsigned long long)hi << 32) | (unsigned long long)lo;
}

// ---------- one-time: pack gate weights k-major ----------
// Wp[k][j] = { Wcat[0*256+j][k], Wcat[1*256+j][k], Wcat[2*256+j][k], Wcat[3*256+j][k] }
// where Wcat[n] = concat(Wih[n] (128), Whh[n] (256)).  Also inits the max scalars.
__global__ void k_pack(const float* __restrict__ Wih, const float* __restrict__ Whh,
                       f32x4* __restrict__ Wp, unsigned* __restrict__ maxWnU,
                       unsigned* __restrict__ maxObU) {
    int k = blockIdx.x;   // 0..383
    int j = threadIdx.x;  // 0..255
    f32x4 v;
#pragma unroll
    for (int g = 0; g < 4; ++g) {
        int n = (g << 8) + j;
        ((float*)&v)[g] = (k < NE) ? Wih[(size_t)n * NE + k] : Whh[(size_t)n * NH + (k - NE)];
    }
    Wp[k * 256 + j] = v;
    if (k == 0 && j == 0) { *maxWnU = 0u; *maxObU = 0u; }
}

// ---------- once: maxWn = max_v ||out_W[v]||_2, mob = max_v outb[v] ----------
__global__ __launch_bounds__(256) void k_wnorm(const float* __restrict__ W,
                                               const float* __restrict__ outb,
                                               unsigned* __restrict__ maxWnU,
                                               unsigned* __restrict__ maxObU) {
    int lane = threadIdx.x & 63;
    int wv = blockIdx.x * 4 + (threadIdx.x >> 6);  // 125*4 = 500 waves * 64 rows = 32000
    float best = 0.f;
    for (int r = wv * 64; r < wv * 64 + 64; r++) {
        const float* row = &W[(size_t)r * NH];
        float p = 0.f;
#pragma unroll
        for (int q = 0; q < 4; q++) {
            float x = row[lane + 64 * q];
            p += x * x;
        }
#pragma unroll
        for (int m = 1; m <= 32; m <<= 1) p += __shfl_xor(p, m, 64);
        best = fmaxf(best, p);
    }
    if (lane == 0) atomicMax(maxWnU, __float_as_uint(sqrtf(best) * 1.0001f + 1e-6f));
    // outb max: 125*256 = 32000 threads, one element each
    float ob = outb[blockIdx.x * 256 + threadIdx.x];
#pragma unroll
    for (int m = 1; m <= 32; m <<= 1) ob = fmaxf(ob, __shfl_xor(ob, m, 64));
    if (lane == 0) atomicMax(maxObU, fkey(ob));
}

// ---------- fused: zero output + extract gumbel candidates per (t,b) row ----------
__global__ __launch_bounds__(256) void k_prep(const float* __restrict__ gu,
                                              const float* __restrict__ outb,
                                              float* __restrict__ out,
                                              int* __restrict__ counts,
                                              float2* __restrict__ cands) {
    __shared__ int cnt;
    __shared__ float2 lc[MAXC];
    int r = blockIdx.x;  // t*NB + b
    int t = r >> 8, b = r & 255;
    int tid = threadIdx.x;
    if (tid == 0) cnt = 0;
    __syncthreads();
    const float4* g4 = (const float4*)gu + (size_t)r * (NV / 4);
    float4* o4 = (float4*)out + ((size_t)b * TT + t) * (NV / 4);
    float4 z = make_float4(0.f, 0.f, 0.f, 0.f);
    for (int i = tid; i < NV / 4; i += 256) {
        float4 u = g4[i];
        o4[i] = z;
        float uv[4] = {u.x, u.y, u.z, u.w};
#pragma unroll
        for (int comp = 0; comp < 4; comp++) {
            if (uv[comp] > UTHR) {
                int k = atomicAdd(&cnt, 1);  // LDS atomic
                if (k < MAXC) {
                    int v = i * 4 + comp;
                    float gm = -logf(-logf(uv[comp] + 1e-10f) + 1e-10f) + outb[v];
                    lc[k] = make_float2(gm, __int_as_float(v));
                }
            }
        }
    }
    __syncthreads();
    int n = cnt > MAXC ? MAXC : cnt;
    if (tid == 0) counts[r] = cnt;  // cnt > MAXC signals fallback
    if (tid < n) cands[(size_t)r * MAXC + tid] = lc[tid];
}

// ---------- candidate chunk (8-wide, double-buffered) ----------
struct Cand8 {
    f32x4 w[8];
    float g[8];
    int v[8];
};
__device__ __forceinline__ void load8(Cand8& cb, const float2* __restrict__ cr, int base,
                                      int nc, const float* __restrict__ W, int lane) {
#pragma unroll
    for (int i = 0; i < 8; ++i) {
        int ci = base + i;
        float2 cd = (ci < nc) ? cr[ci] : make_float2(-1e30f, __int_as_float(0));
        int v = __float_as_int(cd.y);
        cb.g[i] = cd.x;
        cb.v[i] = v;
        cb.w[i] = *(const f32x4*)&W[(size_t)v * NH + (lane << 2)];
    }
}
__device__ __forceinline__ void comp8(const Cand8& cb, f32x4 hx, unsigned long long& bk) {
#pragma unroll
    for (int i = 0; i < 8; ++i) {
        f32x4 pr = hx * cb.w[i];
        float d = pr.x + pr.y + pr.z + pr.w;
#pragma unroll
        for (int m = 1; m <= 32; m <<= 1) d += __shfl_xor(d, m, 64);
        float s = d + cb.g[i];
        unsigned long long key =
            ((unsigned long long)fkey(s) << 32) | (unsigned)(NV - 1 - cb.v[i]);
        if (key > bk) bk = key;  // tie -> smaller idx
    }
}

// ---------- the whole recurrence: one kernel, no grid syncs ----------
// 64 blocks x 256 threads; block owns batch rows r0..r0+3 (independent of all others).
// Thread j owns hidden unit j for all 4 rows (gates i,f,g,o -> cell is thread-local).
// Wave w owns row w's argmax + embedding.
__global__ __launch_bounds__(256) void k_main(
    const float* __restrict__ noise, const float* __restrict__ fcW,
    const float* __restrict__ fcb, const float* __restrict__ embW,
    const f32x4* __restrict__ Wp, const float* __restrict__ bih,
    const float* __restrict__ bhh, const int* __restrict__ counts,
    const float2* __restrict__ cands, const float* __restrict__ W,
    const float* __restrict__ outb, const float* __restrict__ gu,
    const unsigned* __restrict__ maxWnU, const unsigned* __restrict__ maxObU,
    float* __restrict__ out) {
    __shared__ f32x4 xhp[384];       // [k] -> {row0..row3};  k<128: x (embed), k>=128: h
    __shared__ float hrow[4][256];   // row-major h per wave
    __shared__ float ns[256];        // 4 noise rows
    int tid = threadIdx.x;
    int lane = tid & 63, w = tid >> 6;
    int r0 = blockIdx.x << 2;
    int j = tid;  // hidden unit

    float maxWn = __uint_as_float(*maxWnU);
    float mob = unfkey(*maxObU);

    float bsum[4];
#pragma unroll
    for (int g = 0; g < 4; ++g) bsum[g] = bih[(g << 8) + j] + bhh[(g << 8) + j];

    // ---- init: h0 = tanh(fc(noise)), c0 = 0, x0 = embW[PAD] ----
    ns[tid] = noise[r0 * NZ + tid];
    __syncthreads();
    float c_[4], h_[4];
    {
        float fb = fcb[j];
        float a0 = fb, a1 = fb, a2 = fb, a3 = fb;
        const float* fw = &fcW[(size_t)j * NZ];
        for (int k = 0; k < NZ; ++k) {
            float wv = fw[k];
            a0 += ns[k] * wv;
            a1 += ns[64 + k] * wv;
            a2 += ns[128 + k] * wv;
            a3 += ns[192 + k] * wv;
        }
        h_[0] = tanhf(a0); h_[1] = tanhf(a1); h_[2] = tanhf(a2); h_[3] = tanhf(a3);
#pragma unroll
        for (int q = 0; q < 4; ++q) {
            c_[q] = 0.f;
            ((float*)&xhp[128 + j])[q] = h_[q];
        }
    }
    if (j < NE) {
        float v = embW[j];  // embW[PAD_ID=0] row
        f32x4 t4 = {v, v, v, v};
        xhp[j] = t4;
    }
    __syncthreads();

    for (int t = 0; t < TT; ++t) {
        // ---- gates: thread j computes {i,f,g,o}[j] for all 4 rows ----
        f32x4 a0 = {bsum[0], bsum[0], bsum[0], bsum[0]};
        f32x4 a1 = {bsum[1], bsum[1], bsum[1], bsum[1]};
        f32x4 a2 = {bsum[2], bsum[2], bsum[2], bsum[2]};
        f32x4 a3 = {bsum[3], bsum[3], bsum[3], bsum[3]};
        const f32x4* wp = Wp + j;
#pragma unroll 8
        for (int k = 0; k < 384; ++k) {
            f32x4 xv = xhp[k];         // LDS broadcast
            f32x4 wv = wp[k << 8];     // coalesced, L2-resident
            a0 += xv * wv.x;
            a1 += xv * wv.y;
            a2 += xv * wv.z;
            a3 += xv * wv.w;
        }
        __syncthreads();  // all gate reads of xhp done
        // ---- cell (thread-local) ----
#pragma unroll
        for (int q = 0; q < 4; ++q) {
            float is = 1.f / (1.f + expf(-a0[q]));
            float fs = 1.f / (1.f + expf(-a1[q]));
            float gt = tanhf(a2[q]);
            float os = 1.f / (1.f + expf(-a3[q]));
            c_[q] = fs * c_[q] + is * gt;
            h_[q] = os * tanhf(c_[q]);
            ((float*)&xhp[128 + j])[q] = h_[q];
        }
        __syncthreads();  // h visible
        // ---- per-wave: row b = r0 + w ----
        int b = r0 + w;
        int r = t * NB + b;
        float p = 0.f;
#pragma unroll
        for (int m4 = 0; m4 < 4; ++m4) {
            int k = lane + (m4 << 6);
            float hv = ((float*)&xhp[128 + k])[w];
            hrow[w][k] = hv;
            p += hv * hv;
        }
#pragma unroll
        for (int m = 1; m <= 32; m <<= 1) p += __shfl_xor(p, m, 64);
        f32x4 hx = *(const f32x4*)&hrow[w][lane << 2];

        int nc = counts[r];
        unsigned long long bk = 0;
        if (nc >= 1 && nc <= MAXC) {
            const float2* cr = &cands[(size_t)r * MAXC];
            Cand8 A, B;
            load8(A, cr, 0, nc, W, lane);
            for (int base = 0; base < nc; base += 16) {
                if (base + 8 < nc) load8(B, cr, base + 8, nc, W, lane);
                comp8(A, hx, bk);
                if (base + 16 < nc) load8(A, cr, base + 16, nc, W, lane);
                if (base + 8 < nc) comp8(B, hx, bk);
            }
        }
        // certificate: no non-candidate can beat the best candidate
        float D = sqrtf(p) * 1.0001f * maxWn + mob + 0.01f;
        bool ok = (nc >= 1) && (nc <= MAXC) && (unfkey((unsigned)(bk >> 32)) >= GNC + D);
        if (!ok) {  // exact full scan (wave-level); ~never taken
            const float* gur = gu + (size_t)r * NV;
            unsigned long long fk = 0;
            for (int v = lane; v < NV; v += 64) {
                float uv = gur[v];
                float gm = -logf(-logf(uv + 1e-10f) + 1e-10f);
                const float* Wr = W + (size_t)v * NH;
                float d = 0.f;
                for (int k2 = 0; k2 < NH; ++k2) d += hrow[w][k2] * Wr[k2];
                float s = d + outb[v] + gm;
                unsigned long long key =
                    ((unsigned long long)fkey(s) << 32) | (unsigned)(NV - 1 - v);
                if (key > fk) fk = key;
            }
#pragma unroll
            for (int m = 1; m <= 32; m <<= 1) {
                unsigned long long o = sx64(fk, m);
                if (o > fk) fk = o;
            }
            bk = fk;
        }
        int vwin = NV - 1 - (int)(unsigned)(bk & 0xffffffffull);
        if (lane == 0) out[((size_t)b * TT + t) * NV + vwin] = 1.0f;
        // ---- next x = embW[vwin] ----
        if (t + 1 < TT) {
            float e0 = embW[(size_t)vwin * NE + lane];
            float e1 = embW[(size_t)vwin * NE + 64 + lane];
            ((float*)&xhp[lane])[w] = e0;
            ((float*)&xhp[64 + lane])[w] = e1;
        }
        __syncthreads();  // x visible for next gates pass
    }
}

extern "C" void kernel_launch(void* const* d_in, const int* in_sizes, int n_in,
                              void* d_out, int out_size, void* d_ws, size_t ws_size,
                              hipStream_t stream) {
    const float* noise = (const float*)d_in[0];
    const float* gu    = (const float*)d_in[1];
    const float* fcW   = (const float*)d_in[2];
    const float* fcb   = (const float*)d_in[3];
    const float* embW  = (const float*)d_in[4];
    const float* Wih   = (const float*)d_in[5];
    const float* Whh   = (const float*)d_in[6];
    const float* bih   = (const float*)d_in[7];
    const float* bhh   = (const float*)d_in[8];
    const float* outW  = (const float*)d_in[9];
    const float* outb  = (const float*)d_in[10];
    float* out = (float*)d_out;

    float* ws = (float*)d_ws;
    f32x4* Wp        = (f32x4*)ws;                    // 384*256 f32x4 = 393216 f (1.5 MB)
    int* counts      = (int*)(ws + 393216);           // 4096 i32
    unsigned* maxWnU = (unsigned*)(ws + 397312);      // 1 u32
    unsigned* maxObU = (unsigned*)(ws + 397313);      // 1 u32
    float2* cands    = (float2*)(ws + 397320);        // 4096*192 float2 (6 MB), 8B-aligned

    k_pack<<<384, 256, 0, stream>>>(Wih, Whh, Wp, maxWnU, maxObU);
    k_wnorm<<<125, 256, 0, stream>>>(outW, outb, maxWnU, maxObU);
    k_prep<<<TT * NB, 256, 0, stream>>>(gu, outb, out, counts, cands);
    k_main<<<NB / 4, 256, 0, stream>>>(noise, fcW, fcb, embW, Wp, bih, bhh, counts,
                                       cands, outW, outb, gu, maxWnU, maxObU, out);
}